// Round 7
// baseline (525.577 us; speedup 1.0000x reference)
//
#include <hip/hip_runtime.h>
#include <cstdint>

#define BATCHES 8
#define NPTS 2048
#define NF 512
#define KNN 32
#define WAVES 8
#define NPROD 2048   // producer blocks: 8 queries each (1 per wave -> R0 proven shape)
#define NCONS 1024   // consumer blocks: 16 queries each (2 per wave, R1 gather loop)

// R7: block-level producer/consumer with dynamic roles (overlap across CUs).
// R3-R6 lessons: intra-wave fusion of select into gather spills db[32] (R3/R4:
// 64 VGPR + 400-500 MB scratch traffic); single-wave serial producers are
// latency-bound (R6: dependent shuffle chains, VALUBusy 15%, 255us). The only
// proven-fast select is R0/R1's: ONE query per wave, straight-line, db in regs,
// all waves selecting concurrently (TLP hides shuffle latency; ~13us chip VALU).
// So: 3072 blocks, role = global atomic ticket. First 2048 arrivals produce
// (select 8 queries -> lists in ws, device-scope release flag per octet);
// remaining 1024 consume (acquire-spin, gather 16 queries). Role-by-arrival
// => producers never wait, consumers wait only on already-running blocks: no
// deadlock regardless of dispatch order. Producers done by ~8us; gather wall
// ~1 GiB / 27 TB/s L2 ~ 38us dominates => select hides under it.
// ws layout (uint32): [0] role ctr | [16,16+2048) flags | [2064,...) lists
// (16384 x 32 int = 2 MB). Init kernel zeroes ctr+flags each iteration.
// Spill tripwire: WRITE_SIZE ~= 34.9 MB (32 out + 2 lists). FETCH ~= 30 MB.

typedef float vfloat4 __attribute__((ext_vector_type(4)));  // native vec for nt-store

__global__ void knn_init_ws(uint32_t* __restrict__ ws) {
    const int i = blockIdx.x * blockDim.x + threadIdx.x;
    if (i < 16 + NPROD) ws[i] = 0u;   // role counter (+pad) and all flags
}

__global__ __launch_bounds__(512, 4)
void pointnetpp_knn_maxpool(const float* __restrict__ x,
                            const float* __restrict__ points,
                            float* __restrict__ out,
                            uint32_t* __restrict__ ws) {
    __shared__ __align__(16) float    pts4[NPTS * 4];    // [N][4] (producer only)
    __shared__ __align__(16) uint64_t ckey[WAVES][64];   // select scratch
    __shared__ __align__(16) int      tiebuf[WAVES][KNN];// tie-fallback emit
    __shared__ int roleS;

    const int tid  = threadIdx.x;
    const int lane = tid & 63;
    const int w    = tid >> 6;

    if (tid == 0) roleS = (int)atomicAdd(&ws[0], 1u);    // device-scope ticket
    __syncthreads();
    const int role = roleS;

    uint32_t* flags = ws + 16;                 // [2048] one per query-octet
    int*      lists = (int*)(ws + 16 + NPROD); // [16384][KNN]

    if (role < NPROD) {
        // ======================= PRODUCER =======================
        const int b      = role & 7;           // XCD-affine batch
        const int pr     = role >> 3;          // [0,256) octet within batch
        const int lqBase = pr * 8;

        {   // stage points[b] into LDS as [N][4] (pad .w)
            const float* src = points + (size_t)b * NPTS * 3;
            for (int p = tid; p < NPTS; p += 512) {
                float4* d = (float4*)&pts4[p * 4];
                *d = make_float4(src[p * 3 + 0], src[p * 3 + 1], src[p * 3 + 2], 0.f);
            }
        }
        __syncthreads();

        const uint64_t lmlt = (1ull << lane) - 1ull;
        const int    lq = lqBase + w;          // this wave's query (one, straight-line)
        const float4 qp = *(const float4*)&pts4[lq * 4];

        // ---- distances in registers (R0/R1 proven shape) ----
        uint32_t db[32];
        #pragma unroll
        for (int j = 0; j < 32; ++j) {
            const int n = lane + (j << 6);
            const float4 pp = *(const float4*)&pts4[n * 4];
            const float dx = qp.x - pp.x;
            const float dy = qp.y - pp.y;
            const float dz = qp.z - pp.z;
            db[j] = __float_as_uint(dx * dx + dy * dy + dz * dz);
        }

        auto countLE = [&](uint32_t t) -> uint32_t {
            uint32_t c = 0;
            #pragma unroll
            for (int j = 0; j < 32; ++j)
                c += (uint32_t)__builtin_popcountll(__ballot(db[j] <= t));
            return c;
        };

        // compact <=64 keys to LDS, top-32 merge-select (validated R3/R4):
        // 15 bitonic rounds k=2..32 + min-merge; maxpool is order-invariant,
        // set matches ref tie order via (d2,idx) keys. Requires 32<=cthr<=64.
        auto compactSelect = [&](uint32_t thr, uint32_t cthr) -> int {
            uint32_t base = 0;
            #pragma unroll
            for (int j = 0; j < 32; ++j) {
                const bool     p = db[j] <= thr;
                const uint64_t m = __ballot(p);
                if (p) {
                    const int slot = (int)base + (int)__popcll(m & lmlt);
                    ckey[w][slot] = (((uint64_t)db[j]) << 11) | (uint64_t)(lane + (j << 6));
                }
                base += (uint32_t)__builtin_popcountll(m);
            }
            uint64_t key = (lane < (int)cthr) ? ckey[w][lane] : ~0ull;
            #pragma unroll
            for (int k = 2; k <= 32; k <<= 1) {
                #pragma unroll
                for (int j = k >> 1; j > 0; j >>= 1) {
                    const uint64_t other = __shfl_xor((unsigned long long)key, j);
                    const bool takeMin = (((lane & j) == 0) == ((lane & k) == 0));
                    key = ((key < other) == takeMin) ? key : other;
                }
            }
            {
                const uint64_t other = __shfl_xor((unsigned long long)key, 32);
                const uint64_t mn = key < other ? key : other;
                const uint64_t mx = key < other ? other : key;
                key = ((lane & 32) == 0) ? mn : mx;
            }
            return (int)(key & 0x7FFull);
        };

        // exact-tie fallback: all <T, then ==T ascending index (ref tie order)
        auto tieFallback = [&](uint32_t T, int cnt_lt) -> int {
            int base_lt = 0, base_eq = 0;
            #pragma unroll
            for (int j = 0; j < 32; ++j) {
                const bool lt = db[j] < T;
                const bool eq = db[j] == T;
                const uint64_t mlt = __ballot(lt);
                const uint64_t meq = __ballot(eq);
                int slot = -1;
                if (lt)      slot = base_lt + (int)__popcll(mlt & lmlt);
                else if (eq) slot = cnt_lt + base_eq + (int)__popcll(meq & lmlt);
                if (slot >= 0 && slot < KNN) tiebuf[w][slot] = lane + (j << 6);
                base_lt += (int)__popcll(mlt);
                base_eq += (int)__popcll(meq);
            }
            return tiebuf[w][lane & (KNN - 1)];
        };

        int selv;
        {   // per-lane min + 21-round bitonic sort of 64 minima -> probe
            uint32_t lmin = db[0];
            #pragma unroll
            for (int j = 1; j < 32; ++j) lmin = min(lmin, db[j]);
            uint32_t sm = lmin;
            #pragma unroll
            for (int k = 2; k <= 64; k <<= 1) {
                #pragma unroll
                for (int j = k >> 1; j > 0; j >>= 1) {
                    const uint32_t o  = (uint32_t)__shfl_xor((int)sm, j);
                    const uint32_t mn = min(sm, o);
                    const uint32_t mx = max(sm, o);
                    sm = (((lane & j) == 0) == ((lane & k) == 0)) ? mn : mx;
                }
            }
            const uint32_t probe = (uint32_t)__builtin_amdgcn_readlane((int)sm, 31);
            const uint32_t hi0   = (uint32_t)__builtin_amdgcn_readlane((int)sm, 63);

            const uint32_t c1 = countLE(probe);            // >= 32 guaranteed
            if (c1 <= 64u) selv = compactSelect(probe, c1);
            else {
                const uint32_t cs = countLE(hi0);          // >= 64 guaranteed
                if (cs <= 64u) selv = compactSelect(hi0, cs);
                else if (probe == 0u) selv = tieFallback(0u, 0);
                else {
                    uint32_t lo = 0u, hi = probe;          // c(lo)<32, c(hi)>64
                    bool done = false;
                    while (!done && hi - lo > 1u) {
                        const uint32_t mid = lo + ((hi - lo) >> 1);
                        const uint32_t c   = countLE(mid);
                        if (c >= KNN && c <= 64u) { selv = compactSelect(mid, c); done = true; }
                        else if (c > 64u) hi = mid; else lo = mid;
                    }
                    if (!done) selv = tieFallback(hi, (int)countLE(lo));
                }
            }
        }

        const int gq = b * NPTS + lq;
        if (lane < KNN) lists[gq * KNN + lane] = selv;
        __syncthreads();                 // all 8 lists written
        __threadfence();                 // drain to device coherence point
        if (tid == 0)
            __hip_atomic_store(&flags[b * 256 + pr], 1u,
                               __ATOMIC_RELEASE, __HIP_MEMORY_SCOPE_AGENT);
    } else {
        // ======================= CONSUMER =======================
        const int c  = role - NPROD;
        const int b  = c & 7;                  // XCD-affine batch
        const int ch = c >> 3;                 // [0,128)
        const int lq0 = ch * 16 + 2 * w;       // this wave's 2 queries
        const int fo  = b * 256 + ch * 2 + (w >= 4 ? 1 : 0);   // their octet flag

        while (__hip_atomic_load(&flags[fo], __ATOMIC_ACQUIRE,
                                 __HIP_MEMORY_SCOPE_AGENT) == 0u)
            __builtin_amdgcn_s_sleep(8);

        const float* xb = x + (size_t)b * NPTS * NF;
        #pragma unroll 1
        for (int qq = 0; qq < 2; ++qq) {
            const int lq = lq0 + qq;
            const int gq = b * NPTS + lq;
            const int selv = lists[gq * KNN + (lane & (KNN - 1))];

            float4 a0 = make_float4(-INFINITY, -INFINITY, -INFINITY, -INFINITY);
            float4 a1 = a0;
            #pragma unroll 4   // R1's proven no-spill gather shape
            for (int jj = 0; jj < 32; jj += 2) {
                const int n0 = __builtin_amdgcn_readlane(selv, jj)     & (NPTS - 1);
                const int n1 = __builtin_amdgcn_readlane(selv, jj + 1) & (NPTS - 1);
                const float4* r0 = (const float4*)(xb + (size_t)n0 * NF);
                const float4* r1 = (const float4*)(xb + (size_t)n1 * NF);
                const float4 v00 = r0[lane];
                const float4 v01 = r0[lane + 64];
                const float4 v10 = r1[lane];
                const float4 v11 = r1[lane + 64];
                a0.x = fmaxf(fmaxf(a0.x, v00.x), v10.x);
                a0.y = fmaxf(fmaxf(a0.y, v00.y), v10.y);
                a0.z = fmaxf(fmaxf(a0.z, v00.z), v10.z);
                a0.w = fmaxf(fmaxf(a0.w, v00.w), v10.w);
                a1.x = fmaxf(fmaxf(a1.x, v01.x), v11.x);
                a1.y = fmaxf(fmaxf(a1.y, v01.y), v11.y);
                a1.z = fmaxf(fmaxf(a1.z, v01.z), v11.z);
                a1.w = fmaxf(fmaxf(a1.w, v01.w), v11.w);
            }
            vfloat4* orow = (vfloat4*)(out + ((size_t)b * NPTS + lq) * NF);
            __builtin_nontemporal_store(vfloat4{a0.x, a0.y, a0.z, a0.w}, &orow[lane]);
            __builtin_nontemporal_store(vfloat4{a1.x, a1.y, a1.z, a1.w}, &orow[lane + 64]);
        }
    }
}

extern "C" void kernel_launch(void* const* d_in, const int* in_sizes, int n_in,
                              void* d_out, int out_size, void* d_ws, size_t ws_size,
                              hipStream_t stream) {
    const float* x      = (const float*)d_in[0];   // [8, 2048, 512] f32
    const float* points = (const float*)d_in[1];   // [8, 2048, 3]   f32
    float* out          = (float*)d_out;           // [8, 2048, 512] f32
    uint32_t* ws        = (uint32_t*)d_ws;         // needs ~2.06 MB

    knn_init_ws<<<dim3((16 + NPROD + 255) / 256), dim3(256), 0, stream>>>(ws);
    pointnetpp_knn_maxpool<<<dim3(NPROD + NCONS), dim3(512), 0, stream>>>(
        x, points, out, ws);
}

// Round 8
// 143.359 us; speedup vs baseline: 3.6661x; 3.6661x over previous
//
#include <hip/hip_runtime.h>
#include <cstdint>

#define BATCHES 8
#define NPTS 2048
#define NF 512
#define KNN 32
#define WAVES 8

// R8: TWO-PHASE SPLIT (no overlap). R3-R7 post-mortems: every overlap structure
// pays more than the ~23us select it hides (intra-wave fusion: db[32] scratch
// spill, 400-500 MB traffic; wave-role producer: latency-starved or spilled;
// cross-block roles: 451 MB of coherent flag-poll FETCH at 463us). So run each
// phase as its own dispatch in its proven-fast shape:
//   k1 select: 2048 blocks, 1 query/wave, R0 straight-line select (VGPR 32-40,
//              no spill), lists -> ws. 65536 waves of pure VALU, TLP hides all
//              shuffle latency. ~13us chip VALU work.
//   k2 gather: 2048 blocks, 1 query/wave, R1 gather loop, ZERO LDS, no select
//              state. 1 GiB L2 stream / ~30 TB/s ~= 32us.
// Kernel boundary = free device-wide visibility (no flags/fences/polls).
// batch = blockIdx & 7 in both kernels (XCD L2 affinity; x[b]=4MB fits XCD L2).
// Tripwires: k1 WRITE >> 2 MB => spill; k2 dur >> 35us => L2 model wrong.

typedef float vfloat4 __attribute__((ext_vector_type(4)));  // native vec for nt-store

// ======================= PHASE 1: select =======================
__global__ __launch_bounds__(512, 4)
void knn_select(const float* __restrict__ points,
                int* __restrict__ lists) {
    __shared__ __align__(16) float    pts4[NPTS * 4];     // [N][4]: one b128/candidate
    __shared__ __align__(16) uint64_t ckey[WAVES][64];    // compact keys (fast path)
    __shared__ __align__(16) int      tiebuf[WAVES][KNN]; // tie-fallback emit

    const int tid  = threadIdx.x;
    const int lane = tid & 63;
    const int w    = tid >> 6;

    const int b  = blockIdx.x & 7;
    const int pr = blockIdx.x >> 3;          // [0,256) octet within batch
    const int lq = pr * 8 + w;               // this wave's query (one, straight-line)

    // ---- stage points[b] into LDS as [N][4] (pad .w) ----
    {
        const float* src = points + (size_t)b * NPTS * 3;
        for (int p = tid; p < NPTS; p += 512) {
            float4* d = (float4*)&pts4[p * 4];
            *d = make_float4(src[p * 3 + 0], src[p * 3 + 1], src[p * 3 + 2], 0.f);
        }
    }
    __syncthreads();

    const uint64_t lmlt = (1ull << lane) - 1ull;
    const float4   qp   = *(const float4*)&pts4[lq * 4];

    // ---- distances in registers (R0/R1 proven no-spill shape) ----
    uint32_t db[32];
    #pragma unroll
    for (int j = 0; j < 32; ++j) {
        const int n = lane + (j << 6);
        const float4 pp = *(const float4*)&pts4[n * 4];
        const float dx = qp.x - pp.x;
        const float dy = qp.y - pp.y;
        const float dz = qp.z - pp.z;
        db[j] = __float_as_uint(dx * dx + dy * dy + dz * dz);
    }

    auto countLE = [&](uint32_t t) -> uint32_t {
        uint32_t c = 0;
        #pragma unroll
        for (int j = 0; j < 32; ++j)
            c += (uint32_t)__builtin_popcountll(__ballot(db[j] <= t));
        return c;
    };

    // compact <=64 keys to LDS, top-32 merge-select (validated R3/R4/R7):
    // 15 bitonic rounds k=2..32 + min-merge; maxpool is order-invariant,
    // set matches ref tie order via (d2,idx) keys. Requires 32<=cthr<=64.
    auto compactSelect = [&](uint32_t thr, uint32_t cthr) -> int {
        uint32_t base = 0;
        #pragma unroll
        for (int j = 0; j < 32; ++j) {
            const bool     p = db[j] <= thr;
            const uint64_t m = __ballot(p);
            if (p) {
                const int slot = (int)base + (int)__popcll(m & lmlt);
                ckey[w][slot] = (((uint64_t)db[j]) << 11) | (uint64_t)(lane + (j << 6));
            }
            base += (uint32_t)__builtin_popcountll(m);
        }
        uint64_t key = (lane < (int)cthr) ? ckey[w][lane] : ~0ull;
        #pragma unroll
        for (int k = 2; k <= 32; k <<= 1) {
            #pragma unroll
            for (int j = k >> 1; j > 0; j >>= 1) {
                const uint64_t other = __shfl_xor((unsigned long long)key, j);
                const bool takeMin = (((lane & j) == 0) == ((lane & k) == 0));
                key = ((key < other) == takeMin) ? key : other;
            }
        }
        {
            const uint64_t other = __shfl_xor((unsigned long long)key, 32);
            const uint64_t mn = key < other ? key : other;
            const uint64_t mx = key < other ? other : key;
            key = ((lane & 32) == 0) ? mn : mx;
        }
        return (int)(key & 0x7FFull);
    };

    // exact-tie fallback: all <T, then ==T ascending index (ref tie order)
    auto tieFallback = [&](uint32_t T, int cnt_lt) -> int {
        int base_lt = 0, base_eq = 0;
        #pragma unroll
        for (int j = 0; j < 32; ++j) {
            const bool lt = db[j] < T;
            const bool eq = db[j] == T;
            const uint64_t mlt = __ballot(lt);
            const uint64_t meq = __ballot(eq);
            int slot = -1;
            if (lt)      slot = base_lt + (int)__popcll(mlt & lmlt);
            else if (eq) slot = cnt_lt + base_eq + (int)__popcll(meq & lmlt);
            if (slot >= 0 && slot < KNN) tiebuf[w][slot] = lane + (j << 6);
            base_lt += (int)__popcll(mlt);
            base_eq += (int)__popcll(meq);
        }
        return tiebuf[w][lane & (KNN - 1)];
    };

    int selv;
    {   // per-lane min + 21-round bitonic sort of 64 minima -> probe
        uint32_t lmin = db[0];
        #pragma unroll
        for (int j = 1; j < 32; ++j) lmin = min(lmin, db[j]);
        uint32_t sm = lmin;
        #pragma unroll
        for (int k = 2; k <= 64; k <<= 1) {
            #pragma unroll
            for (int j = k >> 1; j > 0; j >>= 1) {
                const uint32_t o  = (uint32_t)__shfl_xor((int)sm, j);
                const uint32_t mn = min(sm, o);
                const uint32_t mx = max(sm, o);
                sm = (((lane & j) == 0) == ((lane & k) == 0)) ? mn : mx;
            }
        }
        const uint32_t probe = (uint32_t)__builtin_amdgcn_readlane((int)sm, 31);
        const uint32_t hi0   = (uint32_t)__builtin_amdgcn_readlane((int)sm, 63);

        const uint32_t c1 = countLE(probe);            // >= 32 guaranteed
        if (c1 <= 64u) selv = compactSelect(probe, c1);
        else {
            const uint32_t cs = countLE(hi0);          // >= 64 guaranteed
            if (cs <= 64u) selv = compactSelect(hi0, cs);
            else if (probe == 0u) selv = tieFallback(0u, 0);
            else {
                uint32_t lo = 0u, hi = probe;          // c(lo)<32 (self), c(hi)>64
                bool done = false;
                while (!done && hi - lo > 1u) {
                    const uint32_t mid = lo + ((hi - lo) >> 1);
                    const uint32_t c   = countLE(mid);
                    if (c >= KNN && c <= 64u) { selv = compactSelect(mid, c); done = true; }
                    else if (c > 64u) hi = mid; else lo = mid;
                }
                if (!done) selv = tieFallback(hi, (int)countLE(lo));
            }
        }
    }

    if (lane < KNN) lists[((size_t)b * NPTS + lq) * KNN + lane] = selv;
}

// ======================= PHASE 2: gather + max-pool =======================
__global__ __launch_bounds__(512, 4)
void knn_gather(const float* __restrict__ x,
                const int* __restrict__ lists,
                float* __restrict__ out) {
    const int tid  = threadIdx.x;
    const int lane = tid & 63;
    const int w    = tid >> 6;

    const int b  = blockIdx.x & 7;           // XCD-affine batch
    const int pr = blockIdx.x >> 3;
    const int lq = pr * 8 + w;               // this wave's query

    const float* xb = x + (size_t)b * NPTS * NF;
    const int selv = lists[((size_t)b * NPTS + lq) * KNN + (lane & (KNN - 1))];

    float4 a0 = make_float4(-INFINITY, -INFINITY, -INFINITY, -INFINITY);
    float4 a1 = a0;
    #pragma unroll 4   // R1's proven no-spill gather shape: 4 rows (8 loads) in flight
    for (int jj = 0; jj < 32; jj += 2) {
        const int n0 = __builtin_amdgcn_readlane(selv, jj)     & (NPTS - 1);
        const int n1 = __builtin_amdgcn_readlane(selv, jj + 1) & (NPTS - 1);
        const float4* r0 = (const float4*)(xb + (size_t)n0 * NF);
        const float4* r1 = (const float4*)(xb + (size_t)n1 * NF);
        const float4 v00 = r0[lane];
        const float4 v01 = r0[lane + 64];
        const float4 v10 = r1[lane];
        const float4 v11 = r1[lane + 64];
        a0.x = fmaxf(fmaxf(a0.x, v00.x), v10.x);
        a0.y = fmaxf(fmaxf(a0.y, v00.y), v10.y);
        a0.z = fmaxf(fmaxf(a0.z, v00.z), v10.z);
        a0.w = fmaxf(fmaxf(a0.w, v00.w), v10.w);
        a1.x = fmaxf(fmaxf(a1.x, v01.x), v11.x);
        a1.y = fmaxf(fmaxf(a1.y, v01.y), v11.y);
        a1.z = fmaxf(fmaxf(a1.z, v01.z), v11.z);
        a1.w = fmaxf(fmaxf(a1.w, v01.w), v11.w);
    }

    vfloat4* orow = (vfloat4*)(out + ((size_t)b * NPTS + lq) * NF);
    __builtin_nontemporal_store(vfloat4{a0.x, a0.y, a0.z, a0.w}, &orow[lane]);
    __builtin_nontemporal_store(vfloat4{a1.x, a1.y, a1.z, a1.w}, &orow[lane + 64]);
}

extern "C" void kernel_launch(void* const* d_in, const int* in_sizes, int n_in,
                              void* d_out, int out_size, void* d_ws, size_t ws_size,
                              hipStream_t stream) {
    const float* x      = (const float*)d_in[0];   // [8, 2048, 512] f32
    const float* points = (const float*)d_in[1];   // [8, 2048, 3]   f32
    float* out          = (float*)d_out;           // [8, 2048, 512] f32
    int*   lists        = (int*)d_ws;              // 16384 x 32 int = 2 MB

    knn_select<<<dim3(BATCHES * (NPTS / WAVES)), dim3(512), 0, stream>>>(points, lists);
    knn_gather<<<dim3(BATCHES * (NPTS / WAVES)), dim3(512), 0, stream>>>(x, lists, out);
}